// Round 10
// baseline (376.384 us; speedup 1.0000x reference)
//
#include <hip/hip_runtime.h>

#define W_  512
#define H_  512
#define HW  (512 * 512)   // 2^18
#define P_  20
#define B_  8
#define TL_ 29
#define IL_ 9

#define NB   1024           // 4 blocks/CU x 256 CU — co-residency proven R4/R5/R6
#define NT   256
#define BPB  (NB / B_)      // 128 blocks per batch
#define TPB  (BPB * NT)     // 32768 threads per batch
#define PPT  (HW / TPB)     // 8 px per thread, TPB-strided (lanes stride-1)

// ws layout (unsigned, 128B-spaced slots), memset to 0 each call:
#define WS_MISMATCH 0
#define WS_GCNT     32
#define WS_GGO      64
#define WS_SCNT     96
#define WS_SGO      128
#define WS_FBAR(b)  (160 + 32 * (b))   // fast per-batch arrive
#define WS_FGO(b)   (448 + 32 * (b))   // fast per-batch go

__device__ __forceinline__ unsigned rel_faa(unsigned* p, unsigned v) {
    return __hip_atomic_fetch_add(p, v, __ATOMIC_RELAXED, __HIP_MEMORY_SCOPE_AGENT);
}
__device__ __forceinline__ void rel_st(unsigned* p, unsigned v) {
    __hip_atomic_store(p, v, __ATOMIC_RELAXED, __HIP_MEMORY_SCOPE_AGENT);
}
__device__ __forceinline__ unsigned rel_ld(unsigned* p) {
    return __hip_atomic_load(p, __ATOMIC_RELAXED, __HIP_MEMORY_SCOPE_AGENT);
}
__device__ __forceinline__ float mall_ldf(const float* p) {   // bypass L1/L2 (coherent pt)
    return __hip_atomic_load(p, __ATOMIC_RELAXED, __HIP_MEMORY_SCOPE_AGENT);
}
__device__ __forceinline__ void mall_stf(float* p, float v) {
    __hip_atomic_store(p, v, __ATOMIC_RELAXED, __HIP_MEMORY_SCOPE_AGENT);
}

// Whole 20-step advect scan, ONE launch. Fast path: batch b lives entirely on
// XCD b (bid&7 under round-robin dispatch) => all carry traffic is intra-L2,
// normal cached ops, fenceless per-batch barriers (__syncthreads drains vmcnt
// before s_barrier, so an arrival implies the block's stores reached L2).
// Runtime guard: if any block's HW_REG_XCC_ID != bid&7, ALL blocks take the
// R6-proven MALL-coherent path (slow but correct) — assignment never affects
// correctness, only speed (G16).
__global__ __launch_bounds__(NT, 4) void fused_scan(
    const float* __restrict__ frames,     // (B, TL, H, W, 1)
    const float* __restrict__ motion,     // (B, 2P, H, W)
    const float* __restrict__ intensity,  // (B, P, H, W)
    float*                    evo_result, // (B, P, H, W) carry — no restrict!
    float* __restrict__       evo_motion, // write-only
    float* __restrict__       motion_out, // write-only copy
    unsigned*                 ws)         // barrier state, zeroed pre-launch
{
    const int bid = blockIdx.x;
    const int b   = bid & 7;
    const int inb = ((bid >> 3) << 8) + threadIdx.x;   // 0..TPB-1 within batch

    // ---- guard: does bid&7 match the physical XCD? ----
    __shared__ unsigned s_flag;
    if (threadIdx.x == 0) {
        unsigned xcc;
        asm volatile("s_getreg_b32 %0, hwreg(HW_REG_XCC_ID)" : "=s"(xcc));
        if ((int)(xcc & 7) != b) rel_st(ws + WS_MISMATCH, 1u);
        asm volatile("s_waitcnt vmcnt(0)" ::: "memory");   // flag store done
    }
    __syncthreads();
    if (threadIdx.x == 0) {                 // global barrier #0 (guard)
        unsigned old = rel_faa(ws + WS_GCNT, 1u);
        if (old + 1 == NB) rel_st(ws + WS_GGO, 1u);
        else while (rel_ld(ws + WS_GGO) < 1u) __builtin_amdgcn_s_sleep(2);
        s_flag = rel_ld(ws + WS_MISMATCH);
        asm volatile("" ::: "memory");
    }
    __syncthreads();
    const bool fast = (s_flag == 0);

    const float* frame0 = frames + ((long)b * TL_ + (IL_ - 1)) * HW;

    for (int p = 0; p < P_; ++p) {
        const float scale = (p == 0) ? 1.0f : 128.0f;
        const float* prev = (p == 0) ? frame0
                                     : evo_result + ((long)b * P_ + (p - 1)) * HW;
        const long moP = ((long)b * (2 * P_) + 2 * p) * HW;
        const long ioP = ((long)b * P_ + p) * HW;

        for (int j = 0; j < PPT; ++j) {
            const int rem = j * TPB + inb;      // lanes stride-1 over pixels
            const int y   = rem >> 9;
            const int x   = rem & (W_ - 1);
            const long mo0 = moP + rem;
            const long io  = ioP + rem;

            const float f0 = __builtin_nontemporal_load(motion + mo0);
            const float f1 = __builtin_nontemporal_load(motion + mo0 + HW);
            const float iv = __builtin_nontemporal_load(intensity + io);
            __builtin_nontemporal_store(f0, motion_out + mo0);
            __builtin_nontemporal_store(f1, motion_out + mo0 + HW);

            const float cx = fminf(fmaxf((float)x + f0, 0.0f), 511.0f);
            const float cy = fminf(fmaxf((float)y + f1, 0.0f), 511.0f);
            const float x0f = floorf(cx), y0f = floorf(cy);
            const float wx = cx - x0f, wy = cy - y0f;
            const int x0 = (int)x0f, y0 = (int)y0f;
            const int x1 = min(x0 + 1, W_ - 1), y1 = min(y0 + 1, H_ - 1);
            const int xi = (int)rintf(cx);      // half-to-even == jnp.round
            const int yi = (int)rintf(cy);

            float v00, v01, v10, v11, vn;
            if (p == 0) {                       // frames: const, cached, any XCD
                v00 = prev[y0 * W_ + x0];  v01 = prev[y0 * W_ + x1];
                v10 = prev[y1 * W_ + x0];  v11 = prev[y1 * W_ + x1];
                vn  = prev[yi * W_ + xi];
            } else if (fast) {                  // intra-XCD L2, normal loads
                v00 = prev[y0 * W_ + x0];  v01 = prev[y0 * W_ + x1];
                v10 = prev[y1 * W_ + x0];  v11 = prev[y1 * W_ + x1];
                vn  = prev[yi * W_ + xi];
            } else {                            // MALL-coherent (R6-proven)
                v00 = mall_ldf(prev + y0 * W_ + x0);
                v01 = mall_ldf(prev + y0 * W_ + x1);
                v10 = mall_ldf(prev + y1 * W_ + x0);
                v11 = mall_ldf(prev + y1 * W_ + x1);
                vn  = mall_ldf(prev + yi * W_ + xi);
            }

            const float bil = scale * ((1.0f - wy) * ((1.0f - wx) * v00 + wx * v01)
                                             + wy  * ((1.0f - wx) * v10 + wx * v11));
            const float res = (scale * vn + iv) * 0.0078125f;   // /128 exact

            if (fast) evo_result[io] = res;     // cached: re-read on same XCD
            else      mall_stf(evo_result + io, res);
            __builtin_nontemporal_store(bil, evo_motion + io);
        }

        if (p != P_ - 1) {
            __syncthreads();                    // drains all waves' vmcnt first
            if (threadIdx.x == 0) {
                const unsigned gen = (unsigned)(p + 1);
                if (fast) {                     // per-batch barrier (128 blocks)
                    unsigned old = rel_faa(ws + WS_FBAR(b), 1u);
                    if (old + 1 == gen * BPB) rel_st(ws + WS_FGO(b), gen);
                    else while (rel_ld(ws + WS_FGO(b)) < gen)
                        __builtin_amdgcn_s_sleep(2);
                } else {                        // global barrier (R6 style)
                    unsigned old = rel_faa(ws + WS_SCNT, 1u);
                    if (old + 1 == gen * NB) rel_st(ws + WS_SGO, gen);
                    else while (rel_ld(ws + WS_SGO) < gen)
                        __builtin_amdgcn_s_sleep(2);
                }
                asm volatile("" ::: "memory");  // no hoisting across the spin
            }
            __syncthreads();
        }
    }
}

extern "C" void kernel_launch(void* const* d_in, const int* in_sizes, int n_in,
                              void* d_out, int out_size, void* d_ws, size_t ws_size,
                              hipStream_t stream)
{
    const float* frames    = (const float*)d_in[0];
    const float* motion    = (const float*)d_in[1];
    const float* intensity = (const float*)d_in[2];

    float* out        = (float*)d_out;
    float* evo_result = out;                          // B*P*HW
    float* evo_motion = out + (long)B_ * P_ * HW;     // B*P*HW
    float* motion_out = out + 2L * B_ * P_ * HW;      // B*2P*HW
    unsigned* ws      = (unsigned*)d_ws;

    hipMemsetAsync(ws, 0, 4096, stream);              // reset all barrier state

    fused_scan<<<dim3(NB), dim3(NT), 0, stream>>>(
        frames, motion, intensity, evo_result, evo_motion, motion_out, ws);
}

// Round 11
// 349.041 us; speedup vs baseline: 1.0783x; 1.0783x over previous
//
#include <hip/hip_runtime.h>

#define W_  512
#define H_  512
#define HW  (512 * 512)   // 2^18
#define P_  20
#define B_  8
#define TL_ 29
#define IL_ 9

#define NB   1024           // 4 blocks/CU x 256 CU — co-residency proven R4/R5/R6/R10
#define NT   256
#define BPB  (NB / B_)      // 128 blocks per batch
#define TPB  (BPB * NT)     // 32768 threads per batch
#define PPT  (HW / TPB)     // 8 px per thread, TPB-strided (lanes stride-1)

// ws layout (unsigned slots), memset to 0 each call:
#define WS_MISMATCH 0
#define WS_GCNT     32
#define WS_GGO      64
#define WS_SCNT     96
#define WS_SGO      128
#define WS_FBAR(b)  (160 + 32 * (b))   // fast per-batch arrive
#define WS_FGO(b)   (448 + 32 * (b))   // fast per-batch go

__device__ __forceinline__ unsigned rel_faa(unsigned* p, unsigned v) {
    return __hip_atomic_fetch_add(p, v, __ATOMIC_RELAXED, __HIP_MEMORY_SCOPE_AGENT);
}
__device__ __forceinline__ void rel_st(unsigned* p, unsigned v) {
    __hip_atomic_store(p, v, __ATOMIC_RELAXED, __HIP_MEMORY_SCOPE_AGENT);
}
__device__ __forceinline__ unsigned rel_ld(unsigned* p) {
    return __hip_atomic_load(p, __ATOMIC_RELAXED, __HIP_MEMORY_SCOPE_AGENT);
}
__device__ __forceinline__ float mall_ldf(const float* p) {
    return __hip_atomic_load(p, __ATOMIC_RELAXED, __HIP_MEMORY_SCOPE_AGENT);
}
__device__ __forceinline__ void mall_stf(float* p, float v) {
    __hip_atomic_store(p, v, __ATOMIC_RELAXED, __HIP_MEMORY_SCOPE_AGENT);
}

// One launch, 20-step advect scan. R11: software-pipelined step boundary —
// step p+1's stream loads (motion x2, intensity) issue BEFORE the barrier, so
// the __syncthreads vmcnt-drain + spin doubles as their latency shadow; the
// j-loop is fully unrolled so all gathers issue as one batch. Barrier protocol
// (per-batch, fenceless, intra-XCD) and XCC_ID guard identical to R10-proven.
__global__ __launch_bounds__(NT, 4) void fused_scan(
    const float* __restrict__ frames,     // (B, TL, H, W, 1)
    const float* __restrict__ motion,     // (B, 2P, H, W)
    const float* __restrict__ intensity,  // (B, P, H, W)
    float*                    evo_result, // (B, P, H, W) carry — no restrict!
    float* __restrict__       evo_motion, // write-only
    float* __restrict__       motion_out, // write-only copy
    unsigned*                 ws)         // barrier state, zeroed pre-launch
{
    const int bid = blockIdx.x;
    const int b   = bid & 7;
    const int inb = ((bid >> 3) << 8) + threadIdx.x;   // 0..TPB-1 within batch

    // ---- guard: does bid&7 match the physical XCD? (G16: never trust mapping)
    __shared__ unsigned s_flag;
    if (threadIdx.x == 0) {
        unsigned xcc;
        asm volatile("s_getreg_b32 %0, hwreg(HW_REG_XCC_ID)" : "=s"(xcc));
        if ((int)(xcc & 7) != b) rel_st(ws + WS_MISMATCH, 1u);
        asm volatile("s_waitcnt vmcnt(0)" ::: "memory");
    }
    __syncthreads();
    if (threadIdx.x == 0) {                 // global guard barrier
        unsigned old = rel_faa(ws + WS_GCNT, 1u);
        if (old + 1 == NB) rel_st(ws + WS_GGO, 1u);
        else while (rel_ld(ws + WS_GGO) < 1u) __builtin_amdgcn_s_sleep(2);
        s_flag = rel_ld(ws + WS_MISMATCH);
        asm volatile("" ::: "memory");
    }
    __syncthreads();
    const bool fast = (s_flag == 0);

    const float* frame0 = frames + ((long)b * TL_ + (IL_ - 1)) * HW;
    const long   ioB    = (long)b * P_ * HW;
    const long   moB    = (long)b * (2 * P_) * HW;

    // pixel coords for the 8 owned pixels (same x, rows 64 apart)
    int rem[PPT];
    #pragma unroll
    for (int j = 0; j < PPT; ++j) rem[j] = j * TPB + inb;

    // ---- prologue: prefetch streams for step 0 ----
    float f0v[PPT], f1v[PPT], ivv[PPT];
    {
        const long moP = moB;            // p=0 flow-x plane
        const long ioP = ioB;
        #pragma unroll
        for (int j = 0; j < PPT; ++j) {
            f0v[j] = __builtin_nontemporal_load(motion + moP + rem[j]);
            f1v[j] = __builtin_nontemporal_load(motion + moP + HW + rem[j]);
            ivv[j] = __builtin_nontemporal_load(intensity + ioP + rem[j]);
        }
    }

    for (int p = 0; p < P_; ++p) {
        const float scale = (p == 0) ? 1.0f : 128.0f;
        const float* prev = (p == 0) ? frame0
                                     : evo_result + ioB + (long)(p - 1) * HW;
        const long moP = moB + (long)(2 * p) * HW;
        const long ioP = ioB + (long)p * HW;

        // copy-out this step's flow planes (values already in regs)
        #pragma unroll
        for (int j = 0; j < PPT; ++j) {
            __builtin_nontemporal_store(f0v[j], motion_out + moP + rem[j]);
            __builtin_nontemporal_store(f1v[j], motion_out + moP + HW + rem[j]);
        }

        // compute + gathers + output stores, fully unrolled (40 gathers batch-issue)
        #pragma unroll
        for (int j = 0; j < PPT; ++j) {
            const int r = rem[j];
            const int y = r >> 9;
            const int x = r & (W_ - 1);

            const float cx = fminf(fmaxf((float)x + f0v[j], 0.0f), 511.0f);
            const float cy = fminf(fmaxf((float)y + f1v[j], 0.0f), 511.0f);
            const float x0f = floorf(cx), y0f = floorf(cy);
            const float wx = cx - x0f, wy = cy - y0f;
            const int x0 = (int)x0f, y0 = (int)y0f;
            const int x1 = min(x0 + 1, W_ - 1), y1 = min(y0 + 1, H_ - 1);
            const int xi = (int)rintf(cx);      // half-to-even == jnp.round
            const int yi = (int)rintf(cy);

            float v00, v01, v10, v11, vn;
            if (fast || p == 0) {               // cached: carry is intra-XCD L2
                v00 = prev[y0 * W_ + x0];  v01 = prev[y0 * W_ + x1];
                v10 = prev[y1 * W_ + x0];  v11 = prev[y1 * W_ + x1];
                vn  = prev[yi * W_ + xi];
            } else {                            // MALL-coherent fallback (R6-proven)
                v00 = mall_ldf(prev + y0 * W_ + x0);
                v01 = mall_ldf(prev + y0 * W_ + x1);
                v10 = mall_ldf(prev + y1 * W_ + x0);
                v11 = mall_ldf(prev + y1 * W_ + x1);
                vn  = mall_ldf(prev + yi * W_ + xi);
            }

            const float bil = scale * ((1.0f - wy) * ((1.0f - wx) * v00 + wx * v01)
                                             + wy  * ((1.0f - wx) * v10 + wx * v11));
            const float res = (scale * vn + ivv[j]) * 0.0078125f;   // /128 exact

            if (fast) evo_result[ioP + r] = res;          // L2-resident for p+1
            else      mall_stf(evo_result + ioP + r, res);
            __builtin_nontemporal_store(bil, evo_motion + ioP + r);
        }

        if (p != P_ - 1) {
            // prefetch next step's streams BEFORE the barrier: they complete
            // during the vmcnt-drain + spin instead of stalling step p+1.
            const long moN = moP + 2 * HW;
            const long ioN = ioP + HW;
            #pragma unroll
            for (int j = 0; j < PPT; ++j) {
                f0v[j] = __builtin_nontemporal_load(motion + moN + rem[j]);
                f1v[j] = __builtin_nontemporal_load(motion + moN + HW + rem[j]);
                ivv[j] = __builtin_nontemporal_load(intensity + ioN + rem[j]);
            }

            __syncthreads();                    // drains stores (and prefetch)
            if (threadIdx.x == 0) {
                const unsigned gen = (unsigned)(p + 1);
                if (fast) {                     // per-batch barrier (128 blocks)
                    unsigned old = rel_faa(ws + WS_FBAR(b), 1u);
                    if (old + 1 == gen * BPB) rel_st(ws + WS_FGO(b), gen);
                    else while (rel_ld(ws + WS_FGO(b)) < gen)
                        __builtin_amdgcn_s_sleep(2);
                } else {                        // global barrier (R6 style)
                    unsigned old = rel_faa(ws + WS_SCNT, 1u);
                    if (old + 1 == gen * NB) rel_st(ws + WS_SGO, gen);
                    else while (rel_ld(ws + WS_SGO) < gen)
                        __builtin_amdgcn_s_sleep(2);
                }
                asm volatile("" ::: "memory");
            }
            __syncthreads();
        }
    }
}

extern "C" void kernel_launch(void* const* d_in, const int* in_sizes, int n_in,
                              void* d_out, int out_size, void* d_ws, size_t ws_size,
                              hipStream_t stream)
{
    const float* frames    = (const float*)d_in[0];
    const float* motion    = (const float*)d_in[1];
    const float* intensity = (const float*)d_in[2];

    float* out        = (float*)d_out;
    float* evo_result = out;                          // B*P*HW
    float* evo_motion = out + (long)B_ * P_ * HW;     // B*P*HW
    float* motion_out = out + 2L * B_ * P_ * HW;      // B*2P*HW
    unsigned* ws      = (unsigned*)d_ws;

    hipMemsetAsync(ws, 0, 4096, stream);              // reset all barrier state

    fused_scan<<<dim3(NB), dim3(NT), 0, stream>>>(
        frames, motion, intensity, evo_result, evo_motion, motion_out, ws);
}

// Round 12
// 339.904 us; speedup vs baseline: 1.1073x; 1.0269x over previous
//
#include <hip/hip_runtime.h>

#define W_  512
#define H_  512
#define HW  (512 * 512)   // 2^18
#define P_  20
#define B_  8
#define TL_ 29
#define IL_ 9

typedef float v2f __attribute__((ext_vector_type(2)));

// One advect step. R12: 2 CONSECUTIVE px/thread -> all stream loads/stores are
// 8 B/lane float2 (G13 sweet spot), halving stream memory instructions.
// Gather lane-stride goes 1->2 (wave footprint ~6->9 lines: mild) — R3's
// failure was stride-8 (32 B/lane, 4-5x footprint). Each block = one image
// row (512 px). Batch->XCD affinity kept (b = bid & 7, proven R8).
// Carry for p>0 reads evo_result[p-1]*128 — exact (pow2 commutes with lerp).
__global__ __launch_bounds__(256) void step_kernel(
    const float* __restrict__ prev_base,   // carry source, per-batch stride prev_stride
    long prev_stride,
    float prev_scale,                      // 1.0 frames / 128.0 evo_result readback
    const float* __restrict__ motion,      // (B, 2P, H, W)
    const float* __restrict__ intensity,   // (B, P, H, W)
    float* __restrict__ evo_result,        // (B, P, H, W)
    float* __restrict__ evo_motion,        // (B, P, H, W)
    float* __restrict__ motion_out,        // (B, 2P, H, W)
    int p)
{
    const int b   = blockIdx.x & 7;        // batch -> XCD (round-robin dispatch)
    const int row = blockIdx.x >> 3;       // 0..511: one row per block
    const int xp  = threadIdx.x << 1;      // first pixel's x (0,2,..,510)
    const int rem = (row << 9) + xp;

    const float* prev = prev_base + (long)b * prev_stride;
    const float yf    = (float)row;

    const long mo0 = ((long)b * (2 * P_) + 2 * p) * HW + rem;  // flow-x plane
    const long io  = ((long)b * P_ + p) * HW + rem;            // intensity/outputs

    const v2f f0 = __builtin_nontemporal_load((const v2f*)(motion + mo0));
    const v2f f1 = __builtin_nontemporal_load((const v2f*)(motion + mo0 + HW));
    const v2f iv = __builtin_nontemporal_load((const v2f*)(intensity + io));

    // motion_ output = pure copy, from registers (float2 stores)
    __builtin_nontemporal_store(f0, (v2f*)(motion_out + mo0));
    __builtin_nontemporal_store(f1, (v2f*)(motion_out + mo0 + HW));

    v2f res, bil;
    #pragma unroll
    for (int j = 0; j < 2; ++j) {
        const float cx = fminf(fmaxf((float)(xp + j) + f0[j], 0.0f), 511.0f);
        const float cy = fminf(fmaxf(yf + f1[j], 0.0f), 511.0f);

        const float x0f = floorf(cx), y0f = floorf(cy);
        const float wx = cx - x0f, wy = cy - y0f;
        const int x0 = (int)x0f, y0 = (int)y0f;
        const int x1 = min(x0 + 1, W_ - 1), y1 = min(y0 + 1, H_ - 1);

        const float* r0 = prev + y0 * W_;
        const float* r1 = prev + y1 * W_;
        const float v00 = r0[x0], v01 = r0[x1];
        const float v10 = r1[x0], v11 = r1[x1];
        bil[j] = prev_scale * ((1.0f - wy) * ((1.0f - wx) * v00 + wx * v01)
                                     + wy  * ((1.0f - wx) * v10 + wx * v11));

        const int xi = (int)rintf(cx);     // half-to-even == jnp.round
        const int yi = (int)rintf(cy);
        res[j] = (prev_scale * prev[yi * W_ + xi] + iv[j]) * 0.0078125f; // /128
    }

    *(v2f*)(evo_result + io) = res;                         // cached: re-read next step
    __builtin_nontemporal_store(bil, (v2f*)(evo_motion + io)); // write-only
}

extern "C" void kernel_launch(void* const* d_in, const int* in_sizes, int n_in,
                              void* d_out, int out_size, void* d_ws, size_t ws_size,
                              hipStream_t stream)
{
    const float* frames    = (const float*)d_in[0];  // (B, TL, H, W, 1)
    const float* motion    = (const float*)d_in[1];  // (B, 2P, H, W)
    const float* intensity = (const float*)d_in[2];  // (B, P, H, W)

    float* out        = (float*)d_out;
    float* evo_result = out;                          // B*P*HW
    float* evo_motion = out + (long)B_ * P_ * HW;     // B*P*HW
    float* motion_out = out + 2L * B_ * P_ * HW;      // B*2P*HW

    const int threads = 256;
    const int blocks  = (B_ * HW) / (threads * 2);    // 4096 = 512 rows x 8 batches

    // step 0: carry = frames[:, IL-1, :, :, 0]
    step_kernel<<<blocks, threads, 0, stream>>>(
        frames + (long)(IL_ - 1) * HW, (long)TL_ * HW, 1.0f,
        motion, intensity, evo_result, evo_motion, motion_out, 0);

    // steps 1..P-1: carry = evo_result[:, p-1] * 128 (exact)
    for (int p = 1; p < P_; ++p) {
        step_kernel<<<blocks, threads, 0, stream>>>(
            evo_result + (long)(p - 1) * HW, (long)P_ * HW, 128.0f,
            motion, intensity, evo_result, evo_motion, motion_out, p);
    }
}

// Round 13
// 333.547 us; speedup vs baseline: 1.1284x; 1.0191x over previous
//
#include <hip/hip_runtime.h>

#define W_  512
#define H_  512
#define HW  (512 * 512)   // 2^18
#define P_  20
#define B_  8
#define TL_ 29
#define IL_ 9

// One advect step, 1 px/thread, lanes stride-1 (R8 = best proven structure).
// R13 change: the nearest gather is ELIMINATED — rint(cx) always selects one
// of the bilinear corners (floor / floor+1, ties-to-even; clamp-consistent),
// so vn is a 4-way cndmask select of already-loaded v00/v01/v10/v11.
// Bit-exact vs the gather. 5 random loads/px -> 4.
// Batch->XCD affinity kept: b = bid & 7 under round-robin dispatch (R8).
// Carry for p>0 reads evo_result[p-1]*128 — exact (pow2 commutes with lerp).
__global__ __launch_bounds__(256) void step_kernel(
    const float* __restrict__ prev_base,   // carry source, per-batch stride prev_stride
    long prev_stride,
    float prev_scale,                      // 1.0 frames / 128.0 evo_result readback
    const float* __restrict__ motion,      // (B, 2P, H, W)
    const float* __restrict__ intensity,   // (B, P, H, W)
    float* __restrict__ evo_result,        // (B, P, H, W)
    float* __restrict__ evo_motion,        // (B, P, H, W)
    float* __restrict__ motion_out,        // (B, 2P, H, W)
    int p)
{
    const int b   = blockIdx.x & 7;                         // batch -> XCD
    const int rem = ((blockIdx.x >> 3) << 8) + threadIdx.x; // pixel within image
    const int y   = rem >> 9;
    const int x   = rem & (W_ - 1);

    const float* prev = prev_base + (long)b * prev_stride;

    const long mo0 = ((long)b * (2 * P_) + 2 * p) * HW + rem;  // flow-x plane
    const long io  = ((long)b * P_ + p) * HW + rem;            // intensity/outputs

    const float f0 = __builtin_nontemporal_load(motion + mo0);
    const float f1 = __builtin_nontemporal_load(motion + mo0 + HW);
    const float iv = __builtin_nontemporal_load(intensity + io);

    // motion_ output = pure copy, from registers
    __builtin_nontemporal_store(f0, motion_out + mo0);
    __builtin_nontemporal_store(f1, motion_out + mo0 + HW);

    const float cx = fminf(fmaxf((float)x + f0, 0.0f), 511.0f);
    const float cy = fminf(fmaxf((float)y + f1, 0.0f), 511.0f);

    const float x0f = floorf(cx), y0f = floorf(cy);
    const float wx = cx - x0f, wy = cy - y0f;
    const int x0 = (int)x0f, y0 = (int)y0f;
    const int x1 = min(x0 + 1, W_ - 1), y1 = min(y0 + 1, H_ - 1);

    const float* r0 = prev + y0 * W_;
    const float* r1 = prev + y1 * W_;
    const float v00 = r0[x0], v01 = r0[x1];
    const float v10 = r1[x0], v11 = r1[x1];
    const float bil = prev_scale * ((1.0f - wy) * ((1.0f - wx) * v00 + wx * v01)
                                          + wy  * ((1.0f - wx) * v10 + wx * v11));

    // nearest == corner select (exactly reproduces rintf half-to-even):
    //   wx>0.5 -> x1; wx<0.5 -> x0; wx==0.5 -> even of {x0,x0+1} (x1 iff x0 odd)
    const bool sx = (wx > 0.5f) || (wx == 0.5f && (x0 & 1));
    const bool sy = (wy > 0.5f) || (wy == 0.5f && (y0 & 1));
    const float vn = sy ? (sx ? v11 : v10) : (sx ? v01 : v00);
    const float res = (prev_scale * vn + iv) * 0.0078125f;   // /128 exact

    evo_result[io] = res;                              // cached: re-read next step
    __builtin_nontemporal_store(bil, evo_motion + io); // write-only
}

extern "C" void kernel_launch(void* const* d_in, const int* in_sizes, int n_in,
                              void* d_out, int out_size, void* d_ws, size_t ws_size,
                              hipStream_t stream)
{
    const float* frames    = (const float*)d_in[0];  // (B, TL, H, W, 1)
    const float* motion    = (const float*)d_in[1];  // (B, 2P, H, W)
    const float* intensity = (const float*)d_in[2];  // (B, P, H, W)

    float* out        = (float*)d_out;
    float* evo_result = out;                          // B*P*HW
    float* evo_motion = out + (long)B_ * P_ * HW;     // B*P*HW
    float* motion_out = out + 2L * B_ * P_ * HW;      // B*2P*HW

    const int threads = 256;
    const int blocks  = (B_ * HW) / threads;          // 8192

    // step 0: carry = frames[:, IL-1, :, :, 0]
    step_kernel<<<blocks, threads, 0, stream>>>(
        frames + (long)(IL_ - 1) * HW, (long)TL_ * HW, 1.0f,
        motion, intensity, evo_result, evo_motion, motion_out, 0);

    // steps 1..P-1: carry = evo_result[:, p-1] * 128 (exact)
    for (int p = 1; p < P_; ++p) {
        step_kernel<<<blocks, threads, 0, stream>>>(
            evo_result + (long)(p - 1) * HW, (long)P_ * HW, 128.0f,
            motion, intensity, evo_result, evo_motion, motion_out, p);
    }
}